// Round 2
// baseline (1319.705 us; speedup 1.0000x reference)
//
#include <hip/hip_runtime.h>
#include <stdint.h>

#define TT 1500
#define DD 512
#define LL 13
#define BB 16
#define NMASK 450   // int(1500*0.3)

typedef __bf16 bf16;
typedef __bf16 bf16x4 __attribute__((ext_vector_type(4)));
typedef __bf16 bf16x8 __attribute__((ext_vector_type(8)));
typedef float f32x4 __attribute__((ext_vector_type(4)));

// ---------------------------------------------------------------------------
// Prep: split lin_w (f32 [L][D][E]) into bf16 hi/lo, in a tiled layout that is
// byte-identical to the LDS image kernel A wants:
//   [l][kt(16)][e(512)][chunk_s(4)][pos(8)]   (32 bf16 of K per e-row)
// 16B-chunk index pre-swizzled with chunk_s ^ ((e>>1)&3): rows alternate bank
// halves via e bit 0 (64B rows), so the XOR must use e bits 1..2 to spread the
// 16-lane frag read across bank slots — (e&3) would leave a 4-way conflict
// (bank bit 5 is lost mod 32). Linear global_load_lds copy + same XOR on the
// ds_read side reproduces k = kg*8..kg*8+7 per (e,kg).  [rule #21: involution
// applied on BOTH source permutation and read address]
// ---------------------------------------------------------------------------
__global__ __launch_bounds__(256) void k_prep(const float* __restrict__ lin_w,
                                              bf16* __restrict__ whi,
                                              bf16* __restrict__ wlo) {
  int tid = blockIdx.x * 256 + threadIdx.x;
  int pos = tid & 7;
  int chunk_s = (tid >> 3) & 3;
  int e = (tid >> 5) & 511;
  int kt = (tid >> 14) & 15;
  int l = tid >> 18;
  if (l >= LL) return;
  int k = ((chunk_s ^ ((e >> 1) & 3)) << 3) | pos;
  int d = (kt << 5) | k;
  float w = lin_w[((size_t)((l << 9) + d) << 9) + e];
  bf16 h = (bf16)w;
  bf16 lo = (bf16)(w - (float)h);
  whi[tid] = h;
  wlo[tid] = lo;
}

// ---------------------------------------------------------------------------
// Scores: per (b,l), scores[t] = attn_w_l . tanh(W_l^T x_t + b_l) + attn_b_l
// 64(t) x 512(e) x 512(k) per block, BK=32, 4 waves, mfma 16x16x32 bf16,
// 3-term hi/lo split (err ~2^-18 rel) for rank-stable ~f32 precision.
// Per kt: B DMA issued first, next-kt A prefetched to regs, then A staged —
// load latency overlaps the vmcnt drain the barrier pays anyway.
// ---------------------------------------------------------------------------
__global__ __launch_bounds__(256, 2) void k_scores(
    const float* __restrict__ reps, const bf16* __restrict__ whi,
    const bf16* __restrict__ wlo, const float* __restrict__ lin_b,
    const float* __restrict__ attn_w, const float* __restrict__ attn_b,
    float* __restrict__ scores) {
  __shared__ __align__(16) bf16 Ah[64 * 32];
  __shared__ __align__(16) bf16 Al[64 * 32];
  __shared__ __align__(16) bf16 Bh[512 * 32];
  __shared__ __align__(16) bf16 Bl[512 * 32];
  __shared__ float sb[512];
  __shared__ float sa[512];
  __shared__ float red[4][64];

  const int tid = threadIdx.x;
  const int wave = tid >> 6;
  const int lane = tid & 63;
  const int ml = lane & 15;
  const int kg = lane >> 4;

  // chunked XCD swizzle: 4992 blocks, 624 contiguous per XCD (4992%8==0)
  const int bid = blockIdx.x;
  const int swz = (bid & 7) * 624 + (bid >> 3);
  const int bl = swz / 24;       // 0..207  (b*13+l)
  const int t0 = (swz % 24) * 64;
  const int l = bl % LL;

  for (int i = tid; i < 512; i += 256) {
    sb[i] = lin_b[(l << 9) + i];
    sa[i] = attn_w[(l << 9) + i];
  }

  f32x4 acc[4][8];
#pragma unroll
  for (int i = 0; i < 4; ++i)
#pragma unroll
    for (int j = 0; j < 8; ++j) acc[i][j] = (f32x4){0.f, 0.f, 0.f, 0.f};

  // A staging: 64 rows x 32 k f32 -> bf16 hi/lo; thread does rows ar, ar+32
  const int ar = tid >> 3;        // 0..31
  const int ac = (tid & 7) << 2;  // float col 0,4,..,28
  int ta0 = t0 + ar;       if (ta0 > TT - 1) ta0 = TT - 1;
  int ta1 = t0 + ar + 32;  if (ta1 > TT - 1) ta1 = TT - 1;
  const float* asrc0 = reps + ((size_t)bl * TT + ta0) * DD + ac;
  const float* asrc1 = reps + ((size_t)bl * TT + ta1) * DD + ac;
  // ((ar+32)>>1)&3 == (ar>>1)&3, so one swizzle term serves both rows
  const int asw = ((ar >> 1) & 3) << 4;
  const int abyte0 = ((ar << 6) + (ac << 1)) ^ asw;
  const int abyte1 = (((ar + 32) << 6) + (ac << 1)) ^ asw;

  const size_t wtile0 = (size_t)l * 16 * 512 * 32;  // bf16 elements
  const int wcol = wave << 7;

  f32x4 xa0 = *(const f32x4*)asrc0;   // kt=0 A prefetch
  f32x4 xa1 = *(const f32x4*)asrc1;

  for (int kt = 0; kt < 16; ++kt) {
    // ---- issue B DMA first: async 16B global->LDS, linear dest ----
    const char* bsrcH = (const char*)(whi + wtile0 + ((size_t)kt << 14));
    const char* bsrcL = (const char*)(wlo + wtile0 + ((size_t)kt << 14));
#pragma unroll
    for (int j = 0; j < 8; ++j) {
      int c = (j << 2) + wave;
      int goff = (c << 10) + lane * 16;
      __builtin_amdgcn_global_load_lds(
          (const __attribute__((address_space(1))) uint32_t*)(bsrcH + goff),
          (__attribute__((address_space(3))) uint32_t*)((char*)Bh + (c << 10)),
          16, 0, 0);
      __builtin_amdgcn_global_load_lds(
          (const __attribute__((address_space(1))) uint32_t*)(bsrcL + goff),
          (__attribute__((address_space(3))) uint32_t*)((char*)Bl + (c << 10)),
          16, 0, 0);
    }
    // ---- prefetch next-kt A into regs (latency hides under B drain) ----
    f32x4 nx0 = xa0, nx1 = xa1;
    if (kt < 15) {
      nx0 = *(const f32x4*)(asrc0 + ((kt + 1) << 5));
      nx1 = *(const f32x4*)(asrc1 + ((kt + 1) << 5));
    }
    // ---- stage current A (f32 -> bf16 hi/lo, swizzled ds_write) ----
#pragma unroll
    for (int half = 0; half < 2; ++half) {
      f32x4 x = half ? xa1 : xa0;
      bf16x4 hv, lv;
#pragma unroll
      for (int j = 0; j < 4; ++j) {
        bf16 h = (bf16)x[j];
        hv[j] = h;
        lv[j] = (bf16)(x[j] - (float)h);
      }
      int ab = half ? abyte1 : abyte0;
      *(bf16x4*)((char*)Ah + ab) = hv;
      *(bf16x4*)((char*)Al + ab) = lv;
    }
    __syncthreads();
    // ---- frags + MFMA ----
    bf16x8 aH[4], aL[4];
#pragma unroll
    for (int rb = 0; rb < 4; ++rb) {
      int row = (rb << 4) + ml;
      int byt = (row << 6) + (kg << 4);
      byt ^= (((row >> 1) & 3) << 4);
      aH[rb] = *(const bf16x8*)((const char*)Ah + byt);
      aL[rb] = *(const bf16x8*)((const char*)Al + byt);
    }
#pragma unroll
    for (int nt = 0; nt < 8; ++nt) {
      int e = wcol + (nt << 4) + ml;
      int byt = (e << 6) + (kg << 4);
      byt ^= (((e >> 1) & 3) << 4);
      bf16x8 bH = *(const bf16x8*)((const char*)Bh + byt);
      bf16x8 bL = *(const bf16x8*)((const char*)Bl + byt);
#pragma unroll
      for (int rb = 0; rb < 4; ++rb) {
        acc[rb][nt] = __builtin_amdgcn_mfma_f32_16x16x32_bf16(aH[rb], bH, acc[rb][nt], 0, 0, 0);
        acc[rb][nt] = __builtin_amdgcn_mfma_f32_16x16x32_bf16(aH[rb], bL, acc[rb][nt], 0, 0, 0);
        acc[rb][nt] = __builtin_amdgcn_mfma_f32_16x16x32_bf16(aL[rb], bH, acc[rb][nt], 0, 0, 0);
      }
    }
    __syncthreads();
    xa0 = nx0;
    xa1 = nx1;
  }

  // ---- epilogue: +bias, tanh, dot attn_w, reduce over e ----
  float part[4][4];
#pragma unroll
  for (int rb = 0; rb < 4; ++rb)
#pragma unroll
    for (int r = 0; r < 4; ++r) part[rb][r] = 0.f;

#pragma unroll
  for (int nt = 0; nt < 8; ++nt) {
    int e = wcol + (nt << 4) + ml;
    float be = sb[e], ae = sa[e];
#pragma unroll
    for (int rb = 0; rb < 4; ++rb)
#pragma unroll
      for (int r = 0; r < 4; ++r) {
        float h = acc[rb][nt][r] + be;
        float th = 1.f - 2.f * __builtin_amdgcn_rcpf(__expf(2.f * h) + 1.f);
        part[rb][r] += th * ae;
      }
  }
#pragma unroll
  for (int rb = 0; rb < 4; ++rb)
#pragma unroll
    for (int r = 0; r < 4; ++r) {
      float v = part[rb][r];
      v += __shfl_xor(v, 1, 64);
      v += __shfl_xor(v, 2, 64);
      v += __shfl_xor(v, 4, 64);
      v += __shfl_xor(v, 8, 64);
      if (ml == 0) red[wave][(rb << 4) + (kg << 2) + r] = v;
    }
  __syncthreads();
  if (tid < 64) {
    int t = t0 + tid;
    if (t < TT) {
      float sc = red[0][tid] + red[1][tid] + red[2][tid] + red[3][tid] + attn_b[l];
      scores[(size_t)bl * TT + t] = sc;
    }
  }
}

// ---------------------------------------------------------------------------
// Coeff: per (b,l): softmax over t; rank via O(T) counting per t (reproduces
// stable argsort-argsort ties: rank[t] = #{s<st} + #{s==st, q<t});
// coeff = mask * attn * c(t) * lw[l]/7500.
// ---------------------------------------------------------------------------
__global__ __launch_bounds__(256) void k_coeff(const float* __restrict__ scores,
                                               const float* __restrict__ lw,
                                               float* __restrict__ coeff) {
  __shared__ float s[TT];
  __shared__ float redm[8];
  const int tid = threadIdx.x;
  const int bl = blockIdx.y;
  const int tc = blockIdx.x;
  const int l = bl % LL;
  const float* src = scores + (size_t)bl * TT;
  for (int i = tid; i < TT; i += 256) s[i] = src[i];
  __syncthreads();

  float m = -3.4e38f;
  for (int i = tid; i < TT; i += 256) m = fmaxf(m, s[i]);
#pragma unroll
  for (int d = 1; d < 64; d <<= 1) m = fmaxf(m, __shfl_xor(m, d, 64));
  if ((tid & 63) == 0) redm[tid >> 6] = m;
  __syncthreads();
  m = fmaxf(fmaxf(redm[0], redm[1]), fmaxf(redm[2], redm[3]));

  float z = 0.f;
  for (int i = tid; i < TT; i += 256) z += __expf(s[i] - m);
#pragma unroll
  for (int d = 1; d < 64; d <<= 1) z += __shfl_xor(z, d, 64);
  if ((tid & 63) == 0) redm[4 + (tid >> 6)] = z;
  __syncthreads();
  z = redm[4] + redm[5] + redm[6] + redm[7];
  const float inv_z = 1.f / z;
  const float scale = lw[l] * (1.f / 7500.f);

  const int t = tc * 250 + tid;
  if (tid < 250 && t < TT) {
    const float st = s[t];
    int cnt = 0;
    for (int q = 0; q < TT; ++q) {
      float sq = s[q];
      cnt += (int)((sq < st) | ((sq == st) & (q < t)));
    }
    int lo2 = t - 2; if (lo2 < 0) lo2 = 0;
    int hi2 = t + 2; if (hi2 > TT - 1) hi2 = TT - 1;
    float c = (float)(hi2 - lo2 + 1);
    float attn = __expf(st - m) * inv_z;
    coeff[(size_t)bl * TT + t] = (cnt >= NMASK) ? attn * c * scale : 0.f;
  }
}

// ---------------------------------------------------------------------------
// Sum: out[b,d] = sum_{l,t} coeff[b,l,t] * reps[b,l,t,d].
// coeff==0 (masked, ~30%) rows are skipped (wave-uniform branch: r is uniform
// within a wave) -> ~30% less HBM read.
// ---------------------------------------------------------------------------
__global__ __launch_bounds__(256) void k_sum(const float* __restrict__ reps,
                                             const float* __restrict__ coeff,
                                             float* __restrict__ out) {
  const int b = blockIdx.y;
  const int r0 = blockIdx.x * 195;           // 100 chunks * 195 = 19500 = L*T
  const int half = threadIdx.x >> 7;         // wave-uniform
  const int dv = (threadIdx.x & 127) << 2;
  const float* Xb = reps + (size_t)b * (LL * TT) * DD;
  const float* cf = coeff + (size_t)b * (LL * TT);
  f32x4 acc = {0.f, 0.f, 0.f, 0.f};
  for (int r = r0 + half; r < r0 + 195; r += 2) {
    float c = cf[r];
    if (c != 0.f) {
      f32x4 x = *(const f32x4*)(Xb + (size_t)r * DD + dv);
      acc += x * c;
    }
  }
  float* o = out + (b << 9) + dv;
  atomicAdd(o + 0, acc[0]);
  atomicAdd(o + 1, acc[1]);
  atomicAdd(o + 2, acc[2]);
  atomicAdd(o + 3, acc[3]);
}

// ---------------------------------------------------------------------------
extern "C" void kernel_launch(void* const* d_in, const int* in_sizes, int n_in,
                              void* d_out, int out_size, void* d_ws, size_t ws_size,
                              hipStream_t stream) {
  const float* reps   = (const float*)d_in[0];
  const float* lin_w  = (const float*)d_in[1];
  const float* lin_b  = (const float*)d_in[2];
  const float* attn_w = (const float*)d_in[3];
  const float* attn_b = (const float*)d_in[4];
  const float* lwts   = (const float*)d_in[5];
  float* out = (float*)d_out;

  char* p = (char*)d_ws;
  const size_t wsz = (size_t)LL * 16 * 512 * 32 * sizeof(bf16);  // 6,815,744 B
  bf16* whi = (bf16*)p;      p += wsz;
  bf16* wlo = (bf16*)p;      p += wsz;
  float* scores = (float*)p; p += (size_t)BB * LL * TT * sizeof(float);
  float* coeff = (float*)p;

  hipMemsetAsync(d_out, 0, (size_t)BB * DD * sizeof(float), stream);
  k_prep<<<dim3((LL * 16 * 512 * 32) / 256), 256, 0, stream>>>(lin_w, whi, wlo);
  k_scores<<<dim3(24 * (BB * LL)), 256, 0, stream>>>(reps, whi, wlo, lin_b,
                                                     attn_w, attn_b, scores);
  k_coeff<<<dim3(6, BB * LL), 256, 0, stream>>>(scores, lwts, coeff);
  k_sum<<<dim3(100, BB), 256, 0, stream>>>(reps, coeff, out);
}